// Round 8
// baseline (68.349 us; speedup 1.0000x reference)
//
#include <hip/hip_runtime.h>
#include <math.h>

// RankingLoss = mean over rows of sum_{pairs: lab_a-lab_b > TOL} lsig(lg_a-lg_b)
//
// lsig(d) = -ln2*log2(1+2^{s_lo - s_hi}),  s = logit*log2e,  E = 2^s.
// log2(1+2^{s_j-s_i}) = log2(E_i + E_j) - s_i   (i = high-label side)
//
// Rows reordered bucket-major by label (bucket width = TOL): for j < C_i
// (C_i = start of bucket b_i - 1) the pair is guaranteed valid with i high.
//   O(N^2) core: p *= (E_i + E_j)  -- 1 v_add (SGPR+VGPR) + 1 v_mul, no LDS,
//   no per-pair VMEM (E_i streams via scalar loads; lanes hold E_j).
//   1 v_log per 8 pairs (product <= 2^63, no overflow; no reassociation).
//   Correction  -s_i*C_i  accumulated exactly (double) in side blocks.
// Side blocks: pairs with C_i <= j < i (bucket distance <= 1, ~3%): exact
//   mask |ld|>TOL + orientation by sign(ld).
// Tiles: per row, i-tiles of 256 (it=0..7), j-tiles of 256 (jt=0..it) ->
//   36 blocks/row; block skips if jbeg >= Cmax, dense if jbeg+256 <= Cmin.
//   row = blockIdx/36 is BLOCK-uniform -> E_i loads are scalar (s_load).

#define NN 2048
#define BB 64
#define TOLF 0.01f
#define BLK 256
#define TILEBLKS (BB * 36)               // 2304
#define SIDEBLKS (BB * 8)                // 512
#define WGRID (TILEBLKS + SIDEBLKS)      // 2816
#define LOG2E 1.4426950408889634f

__device__ float  g_lab[BB][NN];   // labels, bucket-major order
__device__ float  g_s[BB][NN];     // logit * log2e
__device__ float  g_Es[BB][NN];    // 2^s = e^logit
__device__ int    g_C[BB][NN];     // prefix bound: start of bucket b_i - 1
__device__ float  g_part[TILEBLKS];
__device__ double g_partS[SIDEBLKS];

// ---------------- preprocess: bucket-major reorder, one block per row ----------------
__global__ __launch_bounds__(BLK) void rank_pre(const float* __restrict__ logits,
                                                const float* __restrict__ labels) {
    __shared__ int cnt[101], pref[102], offs[101];
    const int row = blockIdx.x;
    const float* lg = logits + (size_t)row * NN;
    const float* lb = labels + (size_t)row * NN;
    for (int x = threadIdx.x; x < 101; x += BLK) { cnt[x] = 0; offs[x] = 0; }
    __syncthreads();
    for (int x = threadIdx.x; x < NN; x += BLK) {
        int b = min(99, (int)(lb[x] * 100.0f));
        atomicAdd(&cnt[b], 1);
    }
    __syncthreads();
    if (threadIdx.x == 0) {
        int r = 0;
        for (int b = 0; b < 101; ++b) { pref[b] = r; r += cnt[b]; }
        pref[101] = r;
    }
    __syncthreads();
    for (int x = threadIdx.x; x < NN; x += BLK) {
        float la = lb[x], lgx = lg[x];
        int b = min(99, (int)(la * 100.0f));
        int p = pref[b] + atomicAdd(&offs[b], 1);
        float s = lgx * LOG2E;
        g_lab[row][p] = la;
        g_s[row][p]   = s;
        g_Es[row][p]  = exp2f(s);
        g_C[row][p]   = (b >= 1) ? pref[b - 1] : 0;
    }
}

// ---------------- main work: tiles (mask-free core) + side (exact) ----------------
__global__ __launch_bounds__(BLK) void rank_work() {
    const int bid = blockIdx.x;
    if (bid < TILEBLKS) {
        const int row = bid / 36;        // block-uniform
        int t = bid % 36;
        int it = 0;
        while ((it + 1) * (it + 2) / 2 <= t) ++it;
        const int jt = t - it * (it + 1) / 2;
        const int ibeg = it * 256;
        const int jbeg = jt * 256;
        const int Cmax = g_C[row][ibeg + 255];   // C monotone in position
        float accL = 0.0f;
        if (jbeg < Cmax) {
            const int Cmin = g_C[row][ibeg];
            const float* __restrict__ Eib = &g_Es[row][ibeg];  // uniform base
            const int*   __restrict__ Cib = &g_C[row][ibeg];
            const int   j  = jbeg + threadIdx.x;
            const float Ej = g_Es[row][j];
            if (jbeg + 256 <= Cmin) {
                // dense: every (i, j) in tile valid, i = high side
                for (int ii = 0; ii < 256; ii += 8) {
                    float p = 1.0f;
#pragma unroll
                    for (int u = 0; u < 8; ++u)
                        p *= (Eib[ii + u] + Ej);        // s_add? no: v_add s,v + v_mul
                    accL += __builtin_amdgcn_logf(p);   // v_log_f32 = log2
                }
            } else {
                // masked: pair counts iff j < C_i
                for (int ii = 0; ii < 256; ii += 8) {
                    float p = 1.0f;
#pragma unroll
                    for (int u = 0; u < 8; ++u) {
                        float tq = (j < Cib[ii + u]) ? (Eib[ii + u] + Ej) : 1.0f;
                        p *= tq;
                    }
                    accL += __builtin_amdgcn_logf(p);
                }
            }
        }
        for (int off = 32; off > 0; off >>= 1) accL += __shfl_down(accL, off);
        __shared__ float swave[4];
        if ((threadIdx.x & 63) == 0) swave[threadIdx.x >> 6] = accL;
        __syncthreads();
        if (threadIdx.x == 0)
            g_part[bid] = swave[0] + swave[1] + swave[2] + swave[3];
    } else {
        // side: bucket-distance <= 1 pairs (exact), plus the -s_i*C_i correction
        const int sb = bid - TILEBLKS;
        const int row = sb >> 3;
        const int i = ((sb & 7) << 8) + threadIdx.x;
        const float lai = g_lab[row][i];
        const float si  = g_s[row][i];
        const int   Ci  = g_C[row][i];
        double acc = -(double)si * (double)Ci;    // exact correction term
        float accf = 0.0f;
        for (int jj = Ci; jj < i; ++jj) {
            float ld = lai - g_lab[row][jj];
            float sj = g_s[row][jj];
            float a  = (ld > 0.0f) ? (sj - si) : (si - sj);
            float tq = (fabsf(ld) > TOLF) ? __builtin_amdgcn_exp2f(a) : 0.0f;
            accf += __builtin_amdgcn_logf(1.0f + tq);
        }
        acc += (double)accf;
        for (int off = 32; off > 0; off >>= 1) acc += __shfl_down(acc, off);
        __shared__ double sdw[4];
        if ((threadIdx.x & 63) == 0) sdw[threadIdx.x >> 6] = acc;
        __syncthreads();
        if (threadIdx.x == 0)
            g_partS[sb] = sdw[0] + sdw[1] + sdw[2] + sdw[3];
    }
}

__global__ __launch_bounds__(BLK) void rank_final(float* __restrict__ out) {
    double acc = 0.0;
    for (int idx = threadIdx.x; idx < TILEBLKS; idx += BLK) acc += (double)g_part[idx];
    for (int idx = threadIdx.x; idx < SIDEBLKS; idx += BLK) acc += g_partS[idx];
    for (int off = 32; off > 0; off >>= 1) acc += __shfl_down(acc, off);
    __shared__ double sw[4];
    if ((threadIdx.x & 63) == 0) sw[threadIdx.x >> 6] = acc;
    __syncthreads();
    if (threadIdx.x == 0)
        out[0] = (float)((sw[0] + sw[1] + sw[2] + sw[3]) *
                         (-0.6931471805599453 / (double)BB));
}

extern "C" void kernel_launch(void* const* d_in, const int* in_sizes, int n_in,
                              void* d_out, int out_size, void* d_ws, size_t ws_size,
                              hipStream_t stream) {
    const float* logits = (const float*)d_in[0];
    const float* labels = (const float*)d_in[1];
    float* out = (float*)d_out;
    (void)in_sizes; (void)n_in; (void)out_size; (void)d_ws; (void)ws_size;

    rank_pre<<<BB, BLK, 0, stream>>>(logits, labels);
    rank_work<<<WGRID, BLK, 0, stream>>>();
    rank_final<<<1, BLK, 0, stream>>>(out);
}

// Round 9
// 42.715 us; speedup vs baseline: 1.6001x; 1.6001x over previous
//
#include <hip/hip_runtime.h>
#include <math.h>

// RankingLoss = mean over rows of sum_{pairs: lab_a-lab_b > TOL} lsig(lg_a-lg_b)
//
// lsig(d) = -ln2*(log2(E_hi + E_lo) - s_hi),  s = logit*log2e, E = 2^s.
// Rows reordered bucket-major by label (bucket width = TOL): for j < C_i
// (C_i = start of bucket b_i-1) the pair is guaranteed valid with i = high.
//   Tile core (j < C_i region): p *= (E_i + E_j), E_i broadcast from LDS,
//   E_j in VGPR, packed v2f -> v_pk_add/v_pk_mul, 2 v_log per 16 pairs.
//   The -s_i part sums to -s_i*C_i per i -> exact O(N) correction (side blk).
//   Side blocks (C_i <= j < i, bucket dist <= 1, ~3%): exact mask |ld|>TOL,
//   term = valid ? (E_i+E_j) : 1 (log(1)=0), corr -= valid ? s_hi : 0.
// Kernels: rank_pre (bucket reorder), rank_work (2304 tile + 512 side blocks),
//          rank_final (reduce, * -ln2 / B).

#define NN 2048
#define BB 64
#define TOLF 0.01f
#define BLK 256
#define NTILE 36                         // lower-triangular 8x8 tiles
#define TILEBLKS (BB * NTILE)            // 2304
#define SIDEBLKS (BB * 8)                // 512
#define WGRID (TILEBLKS + SIDEBLKS)      // 2816
#define LOG2E 1.4426950408889634f

typedef float v2f __attribute__((ext_vector_type(2)));

__device__ float  g_lab[BB][NN];   // labels, bucket-major order
__device__ float  g_s[BB][NN];     // logit * log2e
__device__ float  g_Es[BB][NN];    // 2^s = e^logit
__device__ int    g_C[BB][NN];     // prefix bound: start of bucket b_i - 1
__device__ float  g_part[TILEBLKS];
__device__ double g_partS[SIDEBLKS];

__device__ __forceinline__ v2f mkv2(float a, float b) { v2f r; r.x = a; r.y = b; return r; }

// ---------------- preprocess: bucket-major reorder, one block per row ----------------
__global__ __launch_bounds__(BLK) void rank_pre(const float* __restrict__ logits,
                                                const float* __restrict__ labels) {
    __shared__ int cnt[101], pref[102], offs[101];
    const int row = blockIdx.x;
    const float* lg = logits + (size_t)row * NN;
    const float* lb = labels + (size_t)row * NN;
    for (int x = threadIdx.x; x < 101; x += BLK) { cnt[x] = 0; offs[x] = 0; }
    __syncthreads();
    for (int x = threadIdx.x; x < NN; x += BLK) {
        int b = min(99, (int)(lb[x] * 100.0f));
        atomicAdd(&cnt[b], 1);
    }
    __syncthreads();
    if (threadIdx.x == 0) {
        int r = 0;
        for (int b = 0; b < 101; ++b) { pref[b] = r; r += cnt[b]; }
        pref[101] = r;
    }
    __syncthreads();
    for (int x = threadIdx.x; x < NN; x += BLK) {
        float la = lb[x], lgx = lg[x];
        int b = min(99, (int)(la * 100.0f));
        int p = pref[b] + atomicAdd(&offs[b], 1);
        float s = lgx * LOG2E;
        g_lab[row][p] = la;
        g_s[row][p]   = s;
        g_Es[row][p]  = __builtin_amdgcn_exp2f(s);
        g_C[row][p]   = (b >= 1) ? pref[b - 1] : 0;
    }
}

// ---------------- main work: tiles (mask-free core) + side (exact) ----------------
__global__ __launch_bounds__(BLK) void rank_work() {
    const int bid = blockIdx.x;
    if (bid < TILEBLKS) {
        __shared__ __align__(16) float sE[256];
        __shared__ int   sC[256];
        __shared__ float swave[4];
        const int row = bid / NTILE;          // block-uniform
        int t = bid % NTILE;
        int it = 0;
        while ((it + 1) * (it + 2) / 2 <= t) ++it;
        const int jt = t - it * (it + 1) / 2;
        const int ibeg = it * 256;
        const int jbeg = jt * 256;

        sE[threadIdx.x] = g_Es[row][ibeg + threadIdx.x];
        sC[threadIdx.x] = g_C[row][ibeg + threadIdx.x];
        const float Ej = g_Es[row][jbeg + threadIdx.x];   // lane owns j
        __syncthreads();

        const int Cmax = sC[255];             // C monotone in position
        float accL = 0.0f;
        if (jbeg < Cmax) {
            const int j = jbeg + threadIdx.x;
            if (jbeg + 256 <= sC[0]) {
                // dense: every (i,j) in tile valid, i = high side
                const v2f Ej2 = mkv2(Ej, Ej);
                for (int ii = 0; ii < 256; ii += 16) {
                    const float4* q = (const float4*)&sE[ii];
                    const float4 w0 = q[0], w1 = q[1], w2 = q[2], w3 = q[3];
                    v2f P0 = mkv2(1.0f, 1.0f), P1 = mkv2(1.0f, 1.0f);
                    P0 *= (mkv2(w0.x, w0.y) + Ej2);
                    P1 *= (mkv2(w0.z, w0.w) + Ej2);
                    P0 *= (mkv2(w1.x, w1.y) + Ej2);
                    P1 *= (mkv2(w1.z, w1.w) + Ej2);
                    P0 *= (mkv2(w2.x, w2.y) + Ej2);
                    P1 *= (mkv2(w2.z, w2.w) + Ej2);
                    P0 *= (mkv2(w3.x, w3.y) + Ej2);
                    P1 *= (mkv2(w3.z, w3.w) + Ej2);
                    P0 *= P1;                 // 8 terms/half <= 2^63: no overflow
                    accL += __builtin_amdgcn_logf(P0.x) + __builtin_amdgcn_logf(P0.y);
                }
            } else {
                // masked band: pair counts iff j < C_i
                for (int ii = 0; ii < 256; ii += 8) {
                    float p = 1.0f;
#pragma unroll
                    for (int u = 0; u < 8; ++u) {
                        float term = (j < sC[ii + u]) ? (sE[ii + u] + Ej) : 1.0f;
                        p *= term;
                    }
                    accL += __builtin_amdgcn_logf(p);
                }
            }
        }
        for (int off = 32; off > 0; off >>= 1) accL += __shfl_down(accL, off);
        if ((threadIdx.x & 63) == 0) swave[threadIdx.x >> 6] = accL;
        __syncthreads();
        if (threadIdx.x == 0)
            g_part[bid] = swave[0] + swave[1] + swave[2] + swave[3];
    } else {
        // side: bucket-distance <= 1 pairs (exact) + the -s_i*C_i correction
        __shared__ double sdw[4];
        const int sb = bid - TILEBLKS;
        const int row = sb >> 3;
        const int i = ((sb & 7) << 8) + threadIdx.x;
        const float lai = g_lab[row][i];
        const float si  = g_s[row][i];
        const float Ei  = g_Es[row][i];
        const int   Ci  = g_C[row][i];
        double acc = -(double)si * (double)Ci;    // tile-region -s_hi total
        float accL = 0.0f, accC = 0.0f;
        for (int jj = Ci; jj < i; ++jj) {
            float ld = lai - g_lab[row][jj];
            bool valid = fabsf(ld) > TOLF;
            float term = valid ? (Ei + g_Es[row][jj]) : 1.0f;
            accL += __builtin_amdgcn_logf(term);      // log2; log(1)=0
            float sh = (ld > 0.0f) ? si : g_s[row][jj];
            accC -= valid ? sh : 0.0f;
        }
        acc += (double)accL + (double)accC;
        for (int off = 32; off > 0; off >>= 1) acc += __shfl_down(acc, off);
        if ((threadIdx.x & 63) == 0) sdw[threadIdx.x >> 6] = acc;
        __syncthreads();
        if (threadIdx.x == 0)
            g_partS[sb] = sdw[0] + sdw[1] + sdw[2] + sdw[3];
    }
}

__global__ __launch_bounds__(BLK) void rank_final(float* __restrict__ out) {
    double acc = 0.0;
    for (int idx = threadIdx.x; idx < TILEBLKS; idx += BLK) acc += (double)g_part[idx];
    for (int idx = threadIdx.x; idx < SIDEBLKS; idx += BLK) acc += g_partS[idx];
    for (int off = 32; off > 0; off >>= 1) acc += __shfl_down(acc, off);
    __shared__ double sw[4];
    if ((threadIdx.x & 63) == 0) sw[threadIdx.x >> 6] = acc;
    __syncthreads();
    if (threadIdx.x == 0)
        out[0] = (float)((sw[0] + sw[1] + sw[2] + sw[3]) *
                         (-0.6931471805599453 / (double)BB));
}

extern "C" void kernel_launch(void* const* d_in, const int* in_sizes, int n_in,
                              void* d_out, int out_size, void* d_ws, size_t ws_size,
                              hipStream_t stream) {
    const float* logits = (const float*)d_in[0];
    const float* labels = (const float*)d_in[1];
    float* out = (float*)d_out;
    (void)in_sizes; (void)n_in; (void)out_size; (void)d_ws; (void)ws_size;

    rank_pre<<<BB, BLK, 0, stream>>>(logits, labels);
    rank_work<<<WGRID, BLK, 0, stream>>>();
    rank_final<<<1, BLK, 0, stream>>>(out);
}

// Round 10
// 37.642 us; speedup vs baseline: 1.8158x; 1.1348x over previous
//
#include <hip/hip_runtime.h>
#include <math.h>

// RankingLoss = mean over rows of sum_{pairs: lab_a-lab_b > TOL} lsig(lg_a-lg_b)
//
// lsig(d) = -ln2*(log2(E_hi + E_lo) - s_hi),  s = logit*log2e, E = 2^s.
// Rows reordered bucket-major by label (bucket width = TOL): for j < C_i
// (C_i = start of bucket b_i-1) the pair is guaranteed valid with i = high.
//   Tile core (j < C_i): p *= (E_i + E_j); E_j staged in LDS (uniform-address
//   broadcast reads), E_i per-thread; packed v2f -> v_pk_add/v_pk_mul;
//   2 v_log per 16 pairs (8-term scalar products, <= 2^66, no overflow).
//   The -s_i part sums to -s_i*C_i per i -> exact correction in side blocks.
//   Per-thread trip = clamp(C_i - jbeg, 0, 256); full groups mask-free,
//   one 16-wide masked group covers the remainder.
// Side blocks (C_i <= j < i, bucket distance <= 1, ~3%): exact mask
//   |ld| > TOL; term = valid ? (E_i+E_j) : 1; corr -= valid ? s_hi : 0;
//   product-of-8 log batching.
// Kernels: rank_pre (bucket reorder), rank_work (2304 tile + 512 side),
//          rank_final (reduce, * -ln2 / B).

#define NN 2048
#define BB 64
#define TOLF 0.01f
#define BLK 256
#define NTILE 36                         // lower-triangular 8x8 tiles
#define TILEBLKS (BB * NTILE)            // 2304
#define SIDEBLKS (BB * 8)                // 512
#define WGRID (TILEBLKS + SIDEBLKS)      // 2816
#define LOG2E 1.4426950408889634f

typedef float v2f __attribute__((ext_vector_type(2)));
typedef float v4f __attribute__((ext_vector_type(4)));

__device__ float  g_lab[BB][NN];   // labels, bucket-major order
__device__ float  g_s[BB][NN];     // logit * log2e
__device__ float  g_Es[BB][NN];    // 2^s = e^logit
__device__ int    g_C[BB][NN];     // prefix bound: start of bucket b_i - 1
__device__ float  g_part[TILEBLKS];
__device__ double g_partS[SIDEBLKS];

// ---------------- preprocess: bucket-major reorder, one block per row ----------------
__global__ __launch_bounds__(BLK) void rank_pre(const float* __restrict__ logits,
                                                const float* __restrict__ labels) {
    __shared__ int cnt[101], pref[102], offs[101];
    const int row = blockIdx.x;
    const float* lg = logits + (size_t)row * NN;
    const float* lb = labels + (size_t)row * NN;
    for (int x = threadIdx.x; x < 101; x += BLK) { cnt[x] = 0; offs[x] = 0; }
    __syncthreads();
    for (int x = threadIdx.x; x < NN; x += BLK) {
        int b = min(99, (int)(lb[x] * 100.0f));
        atomicAdd(&cnt[b], 1);
    }
    __syncthreads();
    if (threadIdx.x == 0) {
        int r = 0;
        for (int b = 0; b < 101; ++b) { pref[b] = r; r += cnt[b]; }
        pref[101] = r;
    }
    __syncthreads();
    for (int x = threadIdx.x; x < NN; x += BLK) {
        float la = lb[x], lgx = lg[x];
        int b = min(99, (int)(la * 100.0f));
        int p = pref[b] + atomicAdd(&offs[b], 1);
        float s = lgx * LOG2E;
        g_lab[row][p] = la;
        g_s[row][p]   = s;
        g_Es[row][p]  = __builtin_amdgcn_exp2f(s);
        g_C[row][p]   = (b >= 1) ? pref[b - 1] : 0;
    }
}

// ---------------- main work: tiles (mask-free core) + side (exact) ----------------
__global__ __launch_bounds__(BLK) void rank_work() {
    const int bid = blockIdx.x;
    if (bid < TILEBLKS) {
        __shared__ v4f swin[64];          // 1 KB j-window of E values
        __shared__ float swave[4];
        const int row = bid / NTILE;      // block-uniform
        int t = bid % NTILE;
        int it = 0;
        while ((it + 1) * (it + 2) / 2 <= t) ++it;
        const int jt = t - it * (it + 1) / 2;
        const int ibeg = it * 256;
        const int jbeg = jt * 256;

        for (int x = threadIdx.x; x < 64; x += BLK)
            swin[x] = *(const v4f*)&g_Es[row][jbeg + 4 * x];
        __syncthreads();

        const int i = ibeg + threadIdx.x;
        const float Ei = g_Es[row][i];
        v2f Ei2; Ei2.x = Ei; Ei2.y = Ei;
        int trip = g_C[row][i] - jbeg;
        trip = max(0, min(256, trip));
        const int m16 = trip & ~15;

        float accL = 0.0f;                // log2 units
        for (int jj = 0; jj < m16; jj += 16) {
            const int q = jj >> 2;
            v4f w0 = swin[q + 0], w1 = swin[q + 1];
            v4f w2 = swin[q + 2], w3 = swin[q + 3];
            v2f P0; P0.x = 1.0f; P0.y = 1.0f;
            v2f P1 = P0;
            P0 *= (__builtin_shufflevector(w0, w0, 0, 1) + Ei2);
            P1 *= (__builtin_shufflevector(w0, w0, 2, 3) + Ei2);
            P0 *= (__builtin_shufflevector(w1, w1, 0, 1) + Ei2);
            P1 *= (__builtin_shufflevector(w1, w1, 2, 3) + Ei2);
            P0 *= (__builtin_shufflevector(w2, w2, 0, 1) + Ei2);
            P1 *= (__builtin_shufflevector(w2, w2, 2, 3) + Ei2);
            P0 *= (__builtin_shufflevector(w3, w3, 0, 1) + Ei2);
            P1 *= (__builtin_shufflevector(w3, w3, 2, 3) + Ei2);
            P0 *= P1;                     // 8 scalar terms per half <= 2^66
            accL += __builtin_amdgcn_logf(P0.x) + __builtin_amdgcn_logf(P0.y);
        }
        if (m16 < trip) {
            // masked remainder: fixed 16-wide group, <=15 real terms
            const float* sw = (const float*)swin;
            float p0 = 1.0f, p1 = 1.0f;
#pragma unroll
            for (int u = 0; u < 16; u += 2) {
                float t0 = (m16 + u     < trip) ? (sw[m16 + u]     + Ei) : 1.0f;
                float t1 = (m16 + u + 1 < trip) ? (sw[m16 + u + 1] + Ei) : 1.0f;
                p0 *= t0;
                p1 *= t1;
            }
            accL += __builtin_amdgcn_logf(p0) + __builtin_amdgcn_logf(p1);
        }

        for (int off = 32; off > 0; off >>= 1) accL += __shfl_down(accL, off);
        if ((threadIdx.x & 63) == 0) swave[threadIdx.x >> 6] = accL;
        __syncthreads();
        if (threadIdx.x == 0)
            g_part[bid] = swave[0] + swave[1] + swave[2] + swave[3];
    } else {
        // side: bucket-distance <= 1 pairs (exact) + the -s_i*C_i correction
        __shared__ double sdw[4];
        const int sb = bid - TILEBLKS;
        const int row = sb >> 3;
        const int i = ((sb & 7) << 8) + threadIdx.x;
        const float lai = g_lab[row][i];
        const float si  = g_s[row][i];
        const float Ei  = g_Es[row][i];
        const int   Ci  = g_C[row][i];
        double acc = -(double)si * (double)Ci;    // tile-region -s_hi total
        float accL = 0.0f, accC = 0.0f;
        float p = 1.0f;
        int cntp = 0;
        for (int jj = Ci; jj < i; ++jj) {
            float ld = lai - g_lab[row][jj];
            bool valid = fabsf(ld) > TOLF;
            float term = valid ? (Ei + g_Es[row][jj]) : 1.0f;
            p *= term;
            if (++cntp == 8) { accL += __builtin_amdgcn_logf(p); p = 1.0f; cntp = 0; }
            float sh = (ld > 0.0f) ? si : g_s[row][jj];
            accC -= valid ? sh : 0.0f;
        }
        accL += __builtin_amdgcn_logf(p);
        acc += (double)accL + (double)accC;
        for (int off = 32; off > 0; off >>= 1) acc += __shfl_down(acc, off);
        if ((threadIdx.x & 63) == 0) sdw[threadIdx.x >> 6] = acc;
        __syncthreads();
        if (threadIdx.x == 0)
            g_partS[sb] = sdw[0] + sdw[1] + sdw[2] + sdw[3];
    }
}

__global__ __launch_bounds__(BLK) void rank_final(float* __restrict__ out) {
    double acc = 0.0;
    for (int idx = threadIdx.x; idx < TILEBLKS; idx += BLK) acc += (double)g_part[idx];
    for (int idx = threadIdx.x; idx < SIDEBLKS; idx += BLK) acc += g_partS[idx];
    for (int off = 32; off > 0; off >>= 1) acc += __shfl_down(acc, off);
    __shared__ double sw[4];
    if ((threadIdx.x & 63) == 0) sw[threadIdx.x >> 6] = acc;
    __syncthreads();
    if (threadIdx.x == 0)
        out[0] = (float)((sw[0] + sw[1] + sw[2] + sw[3]) *
                         (-0.6931471805599453 / (double)BB));
}

extern "C" void kernel_launch(void* const* d_in, const int* in_sizes, int n_in,
                              void* d_out, int out_size, void* d_ws, size_t ws_size,
                              hipStream_t stream) {
    const float* logits = (const float*)d_in[0];
    const float* labels = (const float*)d_in[1];
    float* out = (float*)d_out;
    (void)in_sizes; (void)n_in; (void)out_size; (void)d_ws; (void)ws_size;

    rank_pre<<<BB, BLK, 0, stream>>>(logits, labels);
    rank_work<<<WGRID, BLK, 0, stream>>>();
    rank_final<<<1, BLK, 0, stream>>>(out);
}